// Round 3
// baseline (451.396 us; speedup 1.0000x reference)
//
#include <hip/hip_runtime.h>

#define M_DIM 8192   // BATCH * SEQ
#define IN_F  4096
#define RANK_ 1024
#define OUT_F 4096

typedef __bf16 bf16x8 __attribute__((ext_vector_type(8)));
typedef float  f32x4  __attribute__((ext_vector_type(4)));
typedef unsigned short ushort8 __attribute__((ext_vector_type(8)));

__device__ __forceinline__ unsigned short f2bf(float f) {
    unsigned int u = __float_as_uint(f);
    u += 0x7FFFu + ((u >> 16) & 1u);   // round-to-nearest-even
    return (unsigned short)(u >> 16);
}

// ---- fp32 -> bf16 bulk convert (vectorized: 8 elems/thread/iter) ----
__global__ void cvt_f32_bf16(const float* __restrict__ in,
                             unsigned short* __restrict__ out, int n8) {
    int stride = gridDim.x * blockDim.x;
    for (int i = blockIdx.x * blockDim.x + threadIdx.x; i < n8; i += stride) {
        const float4* p = (const float4*)in + (size_t)i * 2;
        float4 a = p[0];
        float4 b = p[1];
        ushort8 o;
        o[0] = f2bf(a.x); o[1] = f2bf(a.y); o[2] = f2bf(a.z); o[3] = f2bf(a.w);
        o[4] = f2bf(b.x); o[5] = f2bf(b.y); o[6] = f2bf(b.z); o[7] = f2bf(b.w);
        ((ushort8*)out)[i] = o;
    }
}

// ---- Vt [IN][RANK] f32 -> VtT [RANK][IN] bf16, scaled by S[r] ----
__global__ void transpose_scale(const float* __restrict__ vt,
                                const float* __restrict__ S,
                                unsigned short* __restrict__ out) {
    __shared__ float tile[32][33];
    const int kb = blockIdx.x * 32;          // over IN
    const int rb = blockIdx.y * 32;          // over RANK
    const int tx = threadIdx.x & 31;
    const int ty = threadIdx.x >> 5;         // 0..7
    #pragma unroll
    for (int j = 0; j < 32; j += 8)
        tile[ty + j][tx] = vt[(size_t)(kb + ty + j) * RANK_ + rb + tx];
    __syncthreads();
    #pragma unroll
    for (int j = 0; j < 32; j += 8) {
        int r = rb + ty + j;
        float s = S[r];
        out[(size_t)r * IN_F + kb + tx] = f2bf(tile[tx][ty + j] * s);
    }
}

// =====================================================================
// 8-phase-style bf16 GEMM: C[M][N] = A[M][K] @ B^T, B is [N][K] row-major.
// BM x BN tile, BK=64, 8 waves (2M x 4N), per-wave 128 x (BN/4).
// Double-buffered LDS, raw s_barrier + counted vmcnt (loads stay in flight
// across barriers; never drain-0 in steady state), 4-quadrant phase-split
// MFMA with setprio, 16B-chunk XOR swizzle (zero bank conflicts, verified
// round 2), bijective XCD blockid swizzle (requires nwg % 8 == 0).
// EPI==0: store bf16.  EPI==1: add bias, store f32.
// =====================================================================
template<int BM, int BN, int EPI>
__global__ __launch_bounds__(512, 2)
void gemm8p(const unsigned short* __restrict__ A,
            const unsigned short* __restrict__ B,
            void* __restrict__ Cv,
            const float* __restrict__ bias,
            int N, int K, int nbx) {
    constexpr int LA = BM / 64;          // gload_lds per thread per A K-tile
    constexpr int LB = BN / 64;          // per B K-tile
    constexpr int L  = LA + LB;          // loads in flight per staged K-tile
    constexpr int NF = BN / 4 / 16;      // per-wave N fragments (WN=4)
    constexpr int NH = NF / 2 > 0 ? NF / 2 : 1;  // frags per N-half

    __shared__ unsigned short sA[2][BM * 64];
    __shared__ unsigned short sB[2][BN * 64];

    const int tid = threadIdx.x;
    const int l = tid & 63;
    const int w = tid >> 6;              // 0..7
    const int wr = w >> 2;               // 0..1  (M)
    const int wc = w & 3;                // 0..3  (N)

    // bijective XCD swizzle (nwg % 8 == 0)
    const int nwg = gridDim.x;
    const int bid = blockIdx.x;
    const int wg  = (bid & 7) * (nwg >> 3) + (bid >> 3);
    const int bx  = wg % nbx;
    const int by  = wg / nbx;
    const int row0 = by * BM;
    const int col0 = bx * BN;

    const unsigned short* gA = A + (size_t)row0 * K;
    const unsigned short* gB = B + (size_t)col0 * K;

    // stage one K-tile (rows x 64) with both-sides XOR swizzle:
    // linear LDS dest + inverse-swizzled global source (rule #21)
    auto stage = [&](const unsigned short* __restrict__ g,
                     unsigned short* __restrict__ s, int k0, int nload) {
        #pragma unroll 4
        for (int i = 0; i < nload; ++i) {
            int chunk = i * 512 + tid;
            int r  = chunk >> 3;
            int c  = chunk & 7;
            int cs = c ^ (r & 7);
            const unsigned short* src = g + (size_t)r * K + k0 + cs * 8;
            __builtin_amdgcn_global_load_lds(
                (const __attribute__((address_space(1))) void*)src,
                (__attribute__((address_space(3))) void*)(s + chunk * 8),
                16, 0, 0);
        }
    };

    f32x4 acc[8][NF];
    const f32x4 z = {0.f, 0.f, 0.f, 0.f};
    #pragma unroll
    for (int i = 0; i < 8; ++i)
        #pragma unroll
        for (int j = 0; j < NF; ++j) acc[i][j] = z;

    const int nt = K >> 6;

    // prologue: stage tiles 0 and 1 into both buffers
    stage(gA, sA[0], 0, LA);
    stage(gB, sB[0], 0, LB);
    stage(gA, sA[1], 64, LA);
    stage(gB, sB[1], 64, LB);
    if constexpr (L == 8) asm volatile("s_waitcnt vmcnt(8)" ::: "memory");
    else                  asm volatile("s_waitcnt vmcnt(6)" ::: "memory");
    __builtin_amdgcn_s_barrier();

    int c = 0;
    for (int t = 0; t < nt; ++t) {
        const unsigned short* a_ = sA[c];
        const unsigned short* b_ = sB[c];
        bf16x8 av[4][2];
        // 4 phases: quadrant q = (M-half, N-half)
        #pragma unroll
        for (int q = 0; q < 4; ++q) {
            const int mh = q >> 1, nh = q & 1;
            if (nh == 0) {
                #pragma unroll
                for (int mi = 0; mi < 4; ++mi)
                    #pragma unroll
                    for (int ks = 0; ks < 2; ++ks) {
                        int r  = wr * 128 + mh * 64 + mi * 16 + (l & 15);
                        int ch = (ks * 4 + (l >> 4)) ^ (r & 7);
                        av[mi][ks] = *(const bf16x8*)((const char*)a_ + r * 128 + ch * 16);
                    }
            }
            bf16x8 bv[NH][2];
            #pragma unroll
            for (int nj = 0; nj < NH; ++nj)
                #pragma unroll
                for (int ks = 0; ks < 2; ++ks) {
                    int r  = wc * (NF * 16) + nh * (NH * 16) + nj * 16 + (l & 15);
                    int ch = (ks * 4 + (l >> 4)) ^ (r & 7);
                    bv[nj][ks] = *(const bf16x8*)((const char*)b_ + r * 128 + ch * 16);
                }
            __builtin_amdgcn_s_barrier();
            __builtin_amdgcn_s_setprio(1);
            #pragma unroll
            for (int mi = 0; mi < 4; ++mi)
                #pragma unroll
                for (int nj = 0; nj < NH; ++nj)
                    #pragma unroll
                    for (int ks = 0; ks < 2; ++ks)
                        acc[mh * 4 + mi][nh * NH + nj] =
                            __builtin_amdgcn_mfma_f32_16x16x32_bf16(
                                av[mi][ks], bv[nj][ks],
                                acc[mh * 4 + mi][nh * NH + nj], 0, 0, 0);
            __builtin_amdgcn_s_setprio(0);
            __builtin_amdgcn_s_barrier();
        }
        // buf[c] fully consumed by all waves (barrier above); restage it
        if (t + 2 < nt) {
            stage(gA, sA[c], (t + 2) << 6, LA);
            stage(gB, sB[c], (t + 2) << 6, LB);
            // wait for tile t+1 (oldest L loads); t+2's stay in flight
            if constexpr (L == 8) asm volatile("s_waitcnt vmcnt(8)" ::: "memory");
            else                  asm volatile("s_waitcnt vmcnt(6)" ::: "memory");
            __builtin_amdgcn_s_barrier();
        } else if (t + 1 < nt) {
            asm volatile("s_waitcnt vmcnt(0)" ::: "memory");
            __builtin_amdgcn_s_barrier();
        }
        c ^= 1;
    }

    // epilogue: C/D layout col = lane&15, row = (lane>>4)*4 + reg  [m89]
    const int cr = (l >> 4) << 2;
    const int cc = l & 15;
    const int mB = row0 + wr * 128;
    const int nB = col0 + wc * (NF * 16);
    if (EPI == 0) {
        unsigned short* C = (unsigned short*)Cv;
        #pragma unroll
        for (int mi = 0; mi < 8; ++mi)
            #pragma unroll
            for (int nj = 0; nj < NF; ++nj) {
                size_t base = (size_t)(mB + mi * 16 + cr) * N + (nB + nj * 16 + cc);
                #pragma unroll
                for (int r = 0; r < 4; ++r)
                    C[base + (size_t)r * N] = f2bf(acc[mi][nj][r]);
            }
    } else {
        float* C = (float*)Cv;
        #pragma unroll
        for (int nj = 0; nj < NF; ++nj) {
            float bvv = bias[nB + nj * 16 + cc];
            #pragma unroll
            for (int mi = 0; mi < 8; ++mi) {
                size_t base = (size_t)(mB + mi * 16 + cr) * N + (nB + nj * 16 + cc);
                #pragma unroll
                for (int r = 0; r < 4; ++r)
                    C[base + (size_t)r * N] = acc[mi][nj][r] + bvv;
            }
        }
    }
}

extern "C" void kernel_launch(void* const* d_in, const int* in_sizes, int n_in,
                              void* d_out, int out_size, void* d_ws, size_t ws_size,
                              hipStream_t stream) {
    const float* x    = (const float*)d_in[0];
    const float* U    = (const float*)d_in[1];
    const float* S    = (const float*)d_in[2];
    const float* Vt   = (const float*)d_in[3];
    const float* bias = (const float*)d_in[4];

    // workspace layout (total 96 MB)
    unsigned short* xb  = (unsigned short*)d_ws;                 // [8192][4096] bf16, 64 MB
    unsigned short* vtT = xb  + (size_t)M_DIM * IN_F;            // [1024][4096] bf16,  8 MB
    unsigned short* ub  = vtT + (size_t)RANK_ * IN_F;            // [4096][1024] bf16,  8 MB
    unsigned short* h   = ub  + (size_t)OUT_F * RANK_;           // [8192][1024] bf16, 16 MB

    hipLaunchKernelGGL(cvt_f32_bf16, dim3(2048), dim3(256), 0, stream,
                       x, xb, (M_DIM * IN_F) / 8);
    hipLaunchKernelGGL(cvt_f32_bf16, dim3(512), dim3(256), 0, stream,
                       U, ub, (OUT_F * RANK_) / 8);
    hipLaunchKernelGGL(transpose_scale, dim3(IN_F / 32, RANK_ / 32), dim3(256), 0, stream,
                       Vt, S, vtT);

    // GEMM1: h[8192][1024] = xb @ vtT^T (K=4096), BM=256 BN=128 -> 256 wgs
    hipLaunchKernelGGL((gemm8p<256, 128, 0>),
                       dim3((RANK_ / 128) * (M_DIM / 256)), dim3(512), 0, stream,
                       xb, vtT, (void*)h, (const float*)nullptr,
                       RANK_, IN_F, RANK_ / 128);
    // GEMM2: y[8192][4096] = h @ ub^T + bias (K=1024), BM=256 BN=256 -> 512 wgs
    hipLaunchKernelGGL((gemm8p<256, 256, 1>),
                       dim3((OUT_F / 256) * (M_DIM / 256)), dim3(512), 0, stream,
                       h, ub, d_out, bias, OUT_F, RANK_, OUT_F / 256);
}